// Round 1
// 499.704 us; speedup vs baseline: 1.5394x; 1.5394x over previous
//
#include <hip/hip_runtime.h>
#include <hip/hip_bf16.h>
#include <hip/hip_fp16.h>
#include <math.h>

#define N_NODES 100000
#define IN_DIM 64
#define EMBED_DIM 128
#define EDGE_DIM 32
#define N_EDGES 1600000

typedef __attribute__((ext_vector_type(8))) short bf16x8;
typedef __attribute__((ext_vector_type(4))) float f32x4;

__device__ __forceinline__ ushort f2bf(float f) {
    union { float f; uint i; } v; v.f = f;
    uint x = v.i;
    return (ushort)((x + 0x7fffu + ((x >> 16) & 1u)) >> 16);  // RNE
}

// ---------------------------------------------------------------------------
// x -> f16 conversion (halves gather footprint + matches pk_add_f16 layout)
// ---------------------------------------------------------------------------
__global__ __launch_bounds__(256) void cvt_x_kernel(
    const float* __restrict__ x, __half* __restrict__ xh)
{
    const int i = blockIdx.x * blockDim.x + threadIdx.x;
    if (i < N_NODES * IN_DIM / 4) {
        float4 v = ((const float4*)x)[i];
        ((__half2*)xh)[2 * i]     = __floats2half2_rn(v.x, v.y);
        ((__half2*)xh)[2 * i + 1] = __floats2half2_rn(v.z, v.w);
    }
}

// ---------------------------------------------------------------------------
// Edge stage: 16 edges per wave, MFMA 16x16x32 bf16 for the edge linear.
//   agg_in[dst[e]]  += relu(x[src[e]] + ea[e]@We_in  + be_in)   (f16 atomics)
//   agg_out[src[e]] += relu(x[dst[e]] + ea[e]@We_out + be_out)  (f16 atomics)
// B-fragment columns are PERMUTED at load time: block t, lane r holds output
// col cp(t,r) = (t>>1)*32 + 2r + (t&1), so blocks (2tp, 2tp+1) form the
// half2 pair (32tp+2r, 32tp+2r+1) lane-locally -> global_atomic_pk_add_f16
// covers 64B per 16-lane quarter (half the atomic lines of the f32 version).
// ---------------------------------------------------------------------------
__global__ __launch_bounds__(256) void edge_kernel(
    const __half* __restrict__ xh, const int* __restrict__ ei,
    const float* __restrict__ ea,
    const float* __restrict__ We_in, const float* __restrict__ be_in,
    const float* __restrict__ We_out, const float* __restrict__ be_out,
    __half* __restrict__ agg_in, __half* __restrict__ agg_out)
{
    const int lane = threadIdx.x & 63;
    const int r = lane & 15;
    const int h = lane >> 4;
    const int wave = threadIdx.x >> 6;

    // Preload B fragments with permuted columns, and biases.
    bf16x8 bIn[4], bOut[4];
    float beI[4], beO[4];
#pragma unroll
    for (int t = 0; t < 4; ++t) {
        const int cp = ((t >> 1) << 5) + (r << 1) + (t & 1);
        const float* p1 = We_in  + (h * 8) * 64 + cp;
        const float* p2 = We_out + (h * 8) * 64 + cp;
        bf16x8 b1v, b2v;
#pragma unroll
        for (int j = 0; j < 8; ++j) {
            b1v[j] = (short)f2bf(p1[j * 64]);
            b2v[j] = (short)f2bf(p2[j * 64]);
        }
        bIn[t] = b1v; bOut[t] = b2v;
        beI[t] = be_in[cp];
        beO[t] = be_out[cp];
    }

    const int nGroups = N_EDGES / 16;
    const int stride = gridDim.x * 4;
    for (int g = blockIdx.x * 4 + wave; g < nGroups; g += stride) {
        const int e0 = g * 16;
        // A fragment: ea[e0 + r][h*8 .. h*8+7] (fp32, 32B contiguous per lane)
        const float* ap = ea + (size_t)(e0 + r) * 32 + h * 8;
        float4 av0 = *(const float4*)ap;
        float4 av1 = *(const float4*)(ap + 4);
        bf16x8 a;
        a[0] = (short)f2bf(av0.x); a[1] = (short)f2bf(av0.y);
        a[2] = (short)f2bf(av0.z); a[3] = (short)f2bf(av0.w);
        a[4] = (short)f2bf(av1.x); a[5] = (short)f2bf(av1.y);
        a[6] = (short)f2bf(av1.z); a[7] = (short)f2bf(av1.w);

        f32x4 cIn[4], cOut[4];
#pragma unroll
        for (int t = 0; t < 4; ++t) {
            f32x4 z = {0.f, 0.f, 0.f, 0.f};
            cIn[t]  = __builtin_amdgcn_mfma_f32_16x16x32_bf16(a, bIn[t],  z, 0, 0, 0);
            cOut[t] = __builtin_amdgcn_mfma_f32_16x16x32_bf16(a, bOut[t], z, 0, 0, 0);
        }

        // Edge indices for this quarter-wave's 4 edges (16B vector loads).
        const int4 s4 = *(const int4*)(ei + e0 + h * 4);
        const int4 d4 = *(const int4*)(ei + N_EDGES + e0 + h * 4);
        const int ss[4] = {s4.x, s4.y, s4.z, s4.w};
        const int dd[4] = {d4.x, d4.y, d4.z, d4.w};

#pragma unroll
        for (int i = 0; i < 4; ++i) {
            const int s = ss[i];
            const int d = dd[i];
#pragma unroll
            for (int tp = 0; tp < 2; ++tp) {
                const int coff = 32 * tp + 2 * r;      // col pair (coff, coff+1)
                // in-direction: gather x[src], scatter to agg_in[dst]
                __half2 xs = *(const __half2*)(xh + (size_t)s * 64 + coff);
                float m0 = fmaxf(__low2float(xs)  + cIn[2 * tp][i]     + beI[2 * tp],     0.0f);
                float m1 = fmaxf(__high2float(xs) + cIn[2 * tp + 1][i] + beI[2 * tp + 1], 0.0f);
                if (m0 != 0.0f || m1 != 0.0f)
                    unsafeAtomicAdd((__half2*)(agg_in + (size_t)d * 64 + coff),
                                    __floats2half2_rn(m0, m1));
                // out-direction: gather x[dst], scatter to agg_out[src]
                __half2 xd = *(const __half2*)(xh + (size_t)d * 64 + coff);
                float n0 = fmaxf(__low2float(xd)  + cOut[2 * tp][i]     + beO[2 * tp],     0.0f);
                float n1 = fmaxf(__high2float(xd) + cOut[2 * tp + 1][i] + beO[2 * tp + 1], 0.0f);
                if (n0 != 0.0f || n1 != 0.0f)
                    unsafeAtomicAdd((__half2*)(agg_out + (size_t)s * 64 + coff),
                                    __floats2half2_rn(n0, n1));
            }
        }
    }
}

// ---------------------------------------------------------------------------
// Node stage: per 16-node group (one wave):
//   h_dir = gelu_exact((x+agg_dir) @ W1 + b1) @ W2
//   out   = 0.5*(h_out+b2_out) + 0.5*(h_in+b2_in) + x @ Wr + br
// ---------------------------------------------------------------------------
#define T_STRIDE 136

__device__ __forceinline__ void gine_mlp(
    const float* __restrict__ x, const __half* __restrict__ agg,
    const float* __restrict__ W1, const float* __restrict__ b1,
    const float* __restrict__ W2,
    int n0, int r, int h, ushort* Tw, f32x4 hAcc[8])
{
    // A fragments of H0 = x + agg (cast to bf16)
    bf16x8 a0[2];
#pragma unroll
    for (int half_ = 0; half_ < 2; ++half_) {
        const int kb = half_ * 32 + h * 8;
        const float*  xp = x   + (size_t)(n0 + r) * 64 + kb;
        const __half* gp = agg + (size_t)(n0 + r) * 64 + kb;
        float4 x0 = *(const float4*)xp;
        float4 x1 = *(const float4*)(xp + 4);
        __half2 g0 = *(const __half2*)(gp);
        __half2 g1 = *(const __half2*)(gp + 2);
        __half2 g2 = *(const __half2*)(gp + 4);
        __half2 g3 = *(const __half2*)(gp + 6);
        bf16x8 v;
        v[0] = (short)f2bf(x0.x + __low2float(g0));
        v[1] = (short)f2bf(x0.y + __high2float(g0));
        v[2] = (short)f2bf(x0.z + __low2float(g1));
        v[3] = (short)f2bf(x0.w + __high2float(g1));
        v[4] = (short)f2bf(x1.x + __low2float(g2));
        v[5] = (short)f2bf(x1.y + __high2float(g2));
        v[6] = (short)f2bf(x1.z + __low2float(g3));
        v[7] = (short)f2bf(x1.w + __high2float(g3));
        a0[half_] = v;
    }

    __threadfence_block();   // previous users of Tw done before overwrite

    // Layer 1: T = gelu(H0 @ W1 + b1) -> LDS (bf16)
#pragma unroll
    for (int t = 0; t < 8; ++t) {
        const float* w1p = W1 + (h * 8) * 128 + 16 * t + r;
        bf16x8 b0v, b1v;
#pragma unroll
        for (int j = 0; j < 8; ++j) {
            b0v[j] = (short)f2bf(w1p[j * 128]);
            b1v[j] = (short)f2bf(w1p[4096 + j * 128]);
        }
        f32x4 acc = {0.f, 0.f, 0.f, 0.f};
        acc = __builtin_amdgcn_mfma_f32_16x16x32_bf16(a0[0], b0v, acc, 0, 0, 0);
        acc = __builtin_amdgcn_mfma_f32_16x16x32_bf16(a0[1], b1v, acc, 0, 0, 0);
        float bias = b1[16 * t + r];
#pragma unroll
        for (int i = 0; i < 4; ++i) {
            float v = acc[i] + bias;
            float g = 0.5f * v * (1.0f + erff(v * 0.70710678118654752f));
            Tw[(h * 4 + i) * T_STRIDE + 16 * t + r] = f2bf(g);
        }
    }

    __threadfence_block();   // T writes visible before reads

    // Layer 2: h = T @ W2   (b2 added by caller)
    bf16x8 aT[4];
#pragma unroll
    for (int ks = 0; ks < 4; ++ks)
        aT[ks] = *(const bf16x8*)(Tw + r * T_STRIDE + ks * 32 + h * 8);
#pragma unroll
    for (int t = 0; t < 8; ++t) {
        const float* w2p = W2 + (h * 8) * 128 + 16 * t + r;
        f32x4 acc = {0.f, 0.f, 0.f, 0.f};
#pragma unroll
        for (int ks = 0; ks < 4; ++ks) {
            bf16x8 bv;
#pragma unroll
            for (int j = 0; j < 8; ++j) bv[j] = (short)f2bf(w2p[(ks * 32 + j) * 128]);
            acc = __builtin_amdgcn_mfma_f32_16x16x32_bf16(aT[ks], bv, acc, 0, 0, 0);
        }
        hAcc[t] = acc;
    }
}

__global__ __launch_bounds__(256) void node_kernel(
    const float* __restrict__ x,
    const __half* __restrict__ agg_in, const __half* __restrict__ agg_out,
    const float* __restrict__ W1_in, const float* __restrict__ b1_in,
    const float* __restrict__ W2_in, const float* __restrict__ b2_in,
    const float* __restrict__ W1_out, const float* __restrict__ b1_out,
    const float* __restrict__ W2_out, const float* __restrict__ b2_out,
    const float* __restrict__ Wr, const float* __restrict__ br,
    float* __restrict__ out)
{
    const int lane = threadIdx.x & 63;
    const int r = lane & 15;
    const int h = lane >> 4;
    const int wave = threadIdx.x >> 6;

    __shared__ __align__(16) ushort Tld[4][16 * T_STRIDE];
    ushort* Tw = &Tld[wave][0];

    const int g = blockIdx.x * 4 + wave;
    if (g >= N_NODES / 16) return;           // no __syncthreads in this kernel
    const int n0 = g * 16;

    f32x4 hIn[8], hOut[8];
    gine_mlp(x, agg_in,  W1_in,  b1_in,  W2_in,  n0, r, h, Tw, hIn);
    gine_mlp(x, agg_out, W1_out, b1_out, W2_out, n0, r, h, Tw, hOut);

    // Root A-fragments from fp32 x
    bf16x8 ar[2];
#pragma unroll
    for (int half_ = 0; half_ < 2; ++half_) {
        const float* xp = x + (size_t)(n0 + r) * 64 + half_ * 32 + h * 8;
        bf16x8 v;
#pragma unroll
        for (int j = 0; j < 8; ++j) v[j] = (short)f2bf(xp[j]);
        ar[half_] = v;
    }

#pragma unroll
    for (int t = 0; t < 8; ++t) {
        const float* wrp = Wr + (h * 8) * 128 + 16 * t + r;
        bf16x8 b0v, b1v;
#pragma unroll
        for (int j = 0; j < 8; ++j) {
            b0v[j] = (short)f2bf(wrp[j * 128]);
            b1v[j] = (short)f2bf(wrp[4096 + j * 128]);
        }
        f32x4 rt = {0.f, 0.f, 0.f, 0.f};
        rt = __builtin_amdgcn_mfma_f32_16x16x32_bf16(ar[0], b0v, rt, 0, 0, 0);
        rt = __builtin_amdgcn_mfma_f32_16x16x32_bf16(ar[1], b1v, rt, 0, 0, 0);

        const int c = 16 * t + r;
        float b2i = b2_in[c];
        float b2o = b2_out[c];
        float brv = br[c];
#pragma unroll
        for (int i = 0; i < 4; ++i) {
            float o = 0.5f * (hOut[t][i] + b2o) + 0.5f * (hIn[t][i] + b2i) + rt[i] + brv;
            out[(size_t)(n0 + h * 4 + i) * 128 + c] = o;
        }
    }
}

extern "C" void kernel_launch(void* const* d_in, const int* in_sizes, int n_in,
                              void* d_out, int out_size, void* d_ws, size_t ws_size,
                              hipStream_t stream) {
    const float* x      = (const float*)d_in[0];
    const int*   ei     = (const int*)d_in[1];
    const float* ea     = (const float*)d_in[2];
    const float* We_in  = (const float*)d_in[3];
    const float* be_in  = (const float*)d_in[4];
    const float* W1_in  = (const float*)d_in[5];
    const float* b1_in  = (const float*)d_in[6];
    const float* W2_in  = (const float*)d_in[7];
    const float* b2_in  = (const float*)d_in[8];
    const float* We_out = (const float*)d_in[9];
    const float* be_out = (const float*)d_in[10];
    const float* W1_out = (const float*)d_in[11];
    const float* b1_out = (const float*)d_in[12];
    const float* W2_out = (const float*)d_in[13];
    const float* b2_out = (const float*)d_in[14];
    const float* Wr     = (const float*)d_in[15];
    const float* br     = (const float*)d_in[16];

    __half* agg_in  = (__half*)d_ws;                      // 12.8 MB
    __half* agg_out = agg_in + (size_t)N_NODES * IN_DIM;  // 12.8 MB
    __half* x_h     = agg_out + (size_t)N_NODES * IN_DIM; // 12.8 MB
    const size_t agg_bytes = (size_t)2 * N_NODES * IN_DIM * sizeof(__half);

    hipMemsetAsync(d_ws, 0, agg_bytes, stream);

    cvt_x_kernel<<<(N_NODES * IN_DIM / 4 + 255) / 256, 256, 0, stream>>>(x, x_h);

    edge_kernel<<<2048, 256, 0, stream>>>(x_h, ei, ea, We_in, be_in, We_out, be_out,
                                          agg_in, agg_out);

    node_kernel<<<(N_NODES / 16 + 3) / 4, 256, 0, stream>>>(
        x, agg_in, agg_out,
        W1_in, b1_in, W2_in, b2_in,
        W1_out, b1_out, W2_out, b2_out,
        Wr, br, (float*)d_out);
}